// Round 8
// baseline (45393.127 us; speedup 1.0000x reference)
//
#include <hip/hip_runtime.h>
#include <math.h>
#include <stdint.h>

// MGU RNN, T=8192, IN=128, H=1024, L=3 — R8: XCD-LOCAL h-chain.
// Layer l lives on XCD l (blockIdx%8 round-robin mapping): 32 WGs x 512
// threads, 1 WG/CU (forced by 144KB LDS). Wave a of WG slot owns 4 units
// jb=32*slot+4a..+3. W_hh exact fp32 in 128 pinned VGPRs/thread; W_ih as
// bf16 pairs in LDS (128KB, RNE-rounded; err ~5e-3 << 0.059 threshold).
// h sync: publish with sc0 sc1 store (write-through: local L2 + MALL);
// poll with sc0 load (coherent per-XCD L2, ~100ns) + every-4th-sweep
// sc0 sc1 MALL fallback -> if %8 placement assumption fails, degrades to
// ~R6 speed instead of deadlocking. Cross-layer x handoff stays on MALL
// (128-row tagged rings, ~112 steps of slack -> off the critical chain),
// polled FUSED with h in one vmcnt window. No s_sleep (R7 showed it hurt).
// Tag fabric unchanged (validated R3-R7): (tag<<32|float-bits) u64 words,
// exact-match tags (0xAA poison never matches -> no init); parity-2 h rows
// (overwrite-safety via the one per-step barrier); amortized ring
// backpressure via MALL progress words.

#define T_STEPS 8192
#define HDIM 1024
#define RING 128

typedef unsigned long long u64;
typedef int v4i __attribute__((ext_vector_type(4)));

__device__ __forceinline__ u64 agload64(const u64* p) {
    return __hip_atomic_load(p, __ATOMIC_RELAXED, __HIP_MEMORY_SCOPE_AGENT);
}
__device__ __forceinline__ void agstore64(u64* p, u64 v) {
    __hip_atomic_store(p, v, __ATOMIC_RELAXED, __HIP_MEMORY_SCOPE_AGENT);
}
__device__ __forceinline__ int agloadi(const int* p) {
    return __hip_atomic_load(p, __ATOMIC_RELAXED, __HIP_MEMORY_SCOPE_AGENT);
}
__device__ __forceinline__ void agstorei(int* p, int v) {
    __hip_atomic_store(p, v, __ATOMIC_RELAXED, __HIP_MEMORY_SCOPE_AGENT);
}
// L2-coherent poll (sc0: bypass L1, hit per-XCD L2)
__device__ __forceinline__ v4i poll1_l2(const u64* p) {
    v4i r;
    asm volatile("global_load_dwordx4 %0, %1, off sc0\n\t"
                 "s_waitcnt vmcnt(0)"
                 : "=v"(r) : "v"(p) : "memory");
    return r;
}
// MALL poll (sc0 sc1: bypass L1+L2 — cross-XCD truth)
__device__ __forceinline__ v4i poll1_mall(const u64* p) {
    v4i r;
    asm volatile("global_load_dwordx4 %0, %1, off sc0 sc1\n\t"
                 "s_waitcnt vmcnt(0)"
                 : "=v"(r) : "v"(p) : "memory");
    return r;
}
// Fused h(L2) + x(MALL) poll in ONE vmcnt window
__device__ __forceinline__ void poll2_lm(const u64* hp, const u64* xp,
                                         v4i& h4, v4i& x4) {
    asm volatile("global_load_dwordx4 %0, %2, off sc0\n\t"
                 "global_load_dwordx4 %1, %3, off sc0 sc1\n\t"
                 "s_waitcnt vmcnt(0)"
                 : "=&v"(h4), "=&v"(x4) : "v"(hp), "v"(xp) : "memory");
}
__device__ __forceinline__ void poll2_mm(const u64* hp, const u64* xp,
                                         v4i& h4, v4i& x4) {
    asm volatile("global_load_dwordx4 %0, %2, off sc0 sc1\n\t"
                 "global_load_dwordx4 %1, %3, off sc0 sc1\n\t"
                 "s_waitcnt vmcnt(0)"
                 : "=&v"(h4), "=&v"(x4) : "v"(hp), "v"(xp) : "memory");
}
__device__ __forceinline__ float dot4(float4 a, float4 b) {
    return a.x * b.x + a.y * b.y + a.z * b.z + a.w * b.w;
}
__device__ __forceinline__ u64 pack(float v, int tag) {
    return ((u64)(unsigned)tag << 32) | (u64)__float_as_uint(v);
}
__device__ __forceinline__ void opaque4(float4& v) {
    asm volatile("" : "+v"(v.x), "+v"(v.y), "+v"(v.z), "+v"(v.w));
}
__device__ __forceinline__ void opaque2(float2& v) {
    asm volatile("" : "+v"(v.x), "+v"(v.y));
}
__device__ __forceinline__ float sel4(float a0, float a1, float a2, float a3, int g) {
    const float t01 = (g & 1) ? a1 : a0;
    const float t23 = (g & 1) ? a3 : a2;
    return (g & 2) ? t23 : t01;
}
// fp32 -> bf16 bits, round-to-nearest-even
__device__ __forceinline__ unsigned short f2bf(float f) {
    unsigned u = __float_as_uint(f);
    return (unsigned short)((u + 0x7fffu + ((u >> 16) & 1u)) >> 16);
}
// acc += bf16lo(w)*x0 + bf16hi(w)*x1
__device__ __forceinline__ void fma2(float& acc, unsigned w, float x0, float x1) {
    acc += __uint_as_float(w << 16) * x0;
    acc += __uint_as_float(w & 0xffff0000u) * x1;
}

// K: input width. L: layer index 0..2.
template <int K, int L>
__device__ void scan_layer(float* __restrict__ s_h,       // [2][HDIM]
                           float* __restrict__ s_x,       // [2][HDIM]
                           unsigned* __restrict__ s_wih,  // [64*512] bf16 pairs
                           const float* __restrict__ S,         // L==0
                           const u64*  __restrict__ xring_in,   // L>0
                           u64*        __restrict__ xring_out,  // L<2
                           float*      __restrict__ xout,       // L==2
                           const float* __restrict__ h0,
                           const float* __restrict__ w_ih,
                           const float* __restrict__ b_ih,
                           const float* __restrict__ w_hh,
                           const float* __restrict__ b_hh,
                           u64* __restrict__ htag,              // [2,H]
                           int* __restrict__ progNext,          // L<2
                           int* __restrict__ progSelf,          // L>0
                           int slot)                            // 0..31
{
    const int tid = threadIdx.x;       // 0..511
    const int a   = tid >> 6;          // wave 0..7
    const int q   = tid & 63;          // lane
    const int jb  = slot * 32 + 4 * a; // wave owns units jb..jb+3

    // ---- W_ih -> LDS as bf16 pairs (K==1024 layers) ----
    if constexpr (K == 1024) {
        const int base = slot * 32;
#pragma unroll 4
        for (int it = 0; it < 64; ++it) {
            const int flat  = tid + 512 * it;       // = (rowid*64+qq)*8 + d
            const int rowid = flat >> 9;
            const int rem   = flat & 511;
            const int qq    = rem >> 3;
            const int d     = rem & 7;
            const int e     = 256 * (d >> 1) + 4 * qq + 2 * (d & 1);
            const int grow  = (rowid < 32) ? (base + rowid)
                                           : (HDIM + base + rowid - 32);
            const float2 v = *(const float2*)(w_ih + (size_t)grow * K + e);
            s_wih[flat] = (unsigned)f2bf(v.x) | ((unsigned)f2bf(v.y) << 16);
        }
    }

    // ---- W_hh rows jb+g (f), H+jb+g (n) -> 128 pinned fp32 VGPRs ----
    float4 wf[4][4], wn[4][4];
#pragma unroll
    for (int g = 0; g < 4; ++g) {
        const float* rf = w_hh + (size_t)(jb + g) * HDIM;
        const float* rn = w_hh + (size_t)(HDIM + jb + g) * HDIM;
#pragma unroll
        for (int m = 0; m < 4; ++m) {
            wf[g][m] = *(const float4*)(rf + 4 * q + 256 * m);
            wn[g][m] = *(const float4*)(rn + 4 * q + 256 * m);
            opaque4(wf[g][m]); opaque4(wn[g][m]);
        }
    }
    float2 wif2[4], win2[4];   // K==128 input weights (fp32, registers)
    if constexpr (K == 128) {
#pragma unroll
        for (int g = 0; g < 4; ++g) {
            wif2[g] = *(const float2*)(w_ih + (size_t)(jb + g) * K + 2 * q);
            win2[g] = *(const float2*)(w_ih + (size_t)(HDIM + jb + g) * K + 2 * q);
            opaque2(wif2[g]); opaque2(win2[g]);
        }
    }
    float bFv[4], bInv[4], bHnv[4];
#pragma unroll
    for (int g = 0; g < 4; ++g) {
        bFv[g]  = b_ih[jb + g] + b_hh[jb + g];
        bInv[g] = b_ih[HDIM + jb + g];
        bHnv[g] = b_hh[HDIM + jb + g];
    }
    __syncthreads();   // s_wih staged

    int lastProg = 0;
    for (int t = 0; t < T_STEPS; ++t) {
        const int par = t & 1;
        const u64* hrow = htag + (size_t)((t + 1) & 1) * HDIM;  // parity t-1
        u64*       hpub = htag + (size_t)par * HDIM;
        float* hD = s_h + par * HDIM;
        float* xD = s_x + par * HDIM;

        // ---- amortized ring backpressure (MALL, off critical path) ----
        if constexpr (L < 2) {
            if (t - lastProg > RING - 16) {
                do { lastProg = agloadi(progNext); } while (t - lastProg > RING - 16);
            }
        }

        // ---- fused poll: h pair (L2-fast + MALL fallback) and x pair ----
        bool hd = (t == 0);
        bool xd = (L == 0);
        if (t == 0) ((float2*)hD)[tid] = ((const float2*)h0)[tid];
        if constexpr (L == 0) {
            if (tid < K / 4)
                ((float4*)xD)[tid] = ((const float4*)(S + (size_t)t * K))[tid];
        }
        {
            const u64* hp = hrow + 2 * tid;
            const u64* xp = (L > 0)
                ? xring_in + (size_t)(t & (RING - 1)) * HDIM + 2 * tid : nullptr;
            const unsigned he = (unsigned)t;
            const unsigned xe = (unsigned)(t + 1);
            float2 hv2 = make_float2(0.f, 0.f), xv2 = make_float2(0.f, 0.f);
            v4i A = {0, 0, 0, 0}, B = {0, 0, 0, 0};
            int it = 0;
            while (!(hd && xd)) {
                const bool mall = ((it & 3) == 3);
                if (!hd && !xd) {
                    if (mall) poll2_mm(hp, xp, A, B); else poll2_lm(hp, xp, A, B);
                } else if (!hd) {
                    A = mall ? poll1_mall(hp) : poll1_l2(hp);
                } else {
                    B = poll1_mall(xp);
                }
                if (!hd && (unsigned)A.y == he && (unsigned)A.w == he) {
                    hv2 = make_float2(__int_as_float(A.x), __int_as_float(A.z));
                    hd = true;
                }
                if (L > 0 && !xd && (unsigned)B.y == xe && (unsigned)B.w == xe) {
                    xv2 = make_float2(__int_as_float(B.x), __int_as_float(B.z));
                    xd = true;
                }
                ++it;
            }
            if (t > 0) ((float2*)hD)[tid] = hv2;
            if constexpr (L > 0) ((float2*)xD)[tid] = xv2;
        }
        __syncthreads();   // the ONE barrier per step

        if constexpr (L > 0) {
            if (slot == 0 && tid == 0) agstorei(progSelf, t + 1);
        }

        // ---- dots for units jb..jb+3 ----
        float4 hq[4];
#pragma unroll
        for (int m = 0; m < 4; ++m) hq[m] = ((const float4*)hD)[q + 64 * m];

        float aF[4]  = {0.f, 0.f, 0.f, 0.f};
        float aNh[4] = {0.f, 0.f, 0.f, 0.f};
        float aNi[4] = {0.f, 0.f, 0.f, 0.f};
#pragma unroll
        for (int m = 0; m < 4; ++m) {
#pragma unroll
            for (int g = 0; g < 4; ++g) {
                aF[g]  += dot4(wf[g][m], hq[m]);
                aNh[g] += dot4(wn[g][m], hq[m]);
            }
        }
        if constexpr (K == 1024) {
            float4 xq[4];
#pragma unroll
            for (int m = 0; m < 4; ++m) xq[m] = ((const float4*)xD)[q + 64 * m];
#pragma unroll
            for (int g = 0; g < 4; ++g) {
                const int u = 4 * a + g;
                const unsigned* wrF = &s_wih[(size_t)(u * 64 + q) * 8];
                const unsigned* wrN = &s_wih[(size_t)((32 + u) * 64 + q) * 8];
                const uint4 F0 = *(const uint4*)wrF;
                const uint4 F1 = *(const uint4*)(wrF + 4);
                const uint4 N0 = *(const uint4*)wrN;
                const uint4 N1 = *(const uint4*)(wrN + 4);
                fma2(aF[g], F0.x, xq[0].x, xq[0].y);
                fma2(aF[g], F0.y, xq[0].z, xq[0].w);
                fma2(aF[g], F0.z, xq[1].x, xq[1].y);
                fma2(aF[g], F0.w, xq[1].z, xq[1].w);
                fma2(aF[g], F1.x, xq[2].x, xq[2].y);
                fma2(aF[g], F1.y, xq[2].z, xq[2].w);
                fma2(aF[g], F1.z, xq[3].x, xq[3].y);
                fma2(aF[g], F1.w, xq[3].z, xq[3].w);
                fma2(aNi[g], N0.x, xq[0].x, xq[0].y);
                fma2(aNi[g], N0.y, xq[0].z, xq[0].w);
                fma2(aNi[g], N0.z, xq[1].x, xq[1].y);
                fma2(aNi[g], N0.w, xq[1].z, xq[1].w);
                fma2(aNi[g], N1.x, xq[2].x, xq[2].y);
                fma2(aNi[g], N1.y, xq[2].z, xq[2].w);
                fma2(aNi[g], N1.z, xq[3].x, xq[3].y);
                fma2(aNi[g], N1.w, xq[3].z, xq[3].w);
            }
        } else {
            const float2 x2 = ((const float2*)xD)[q];
#pragma unroll
            for (int g = 0; g < 4; ++g) {
                aF[g]  += wif2[g].x * x2.x + wif2[g].y * x2.y;
                aNi[g] += win2[g].x * x2.x + win2[g].y * x2.y;
            }
        }

        // ---- two-phase reduction (R5-validated): quad butterfly, select,
        //      stride butterfly. Every lane ends with unit (q&3)'s sums. ----
#pragma unroll
        for (int g = 0; g < 4; ++g) {
            aF[g]  += __shfl_xor(aF[g], 1, 64);  aF[g]  += __shfl_xor(aF[g], 2, 64);
            aNh[g] += __shfl_xor(aNh[g], 1, 64); aNh[g] += __shfl_xor(aNh[g], 2, 64);
            aNi[g] += __shfl_xor(aNi[g], 1, 64); aNi[g] += __shfl_xor(aNi[g], 2, 64);
        }
        const int gs = q & 3;
        float vF  = sel4(aF[0],  aF[1],  aF[2],  aF[3],  gs);
        float vNh = sel4(aNh[0], aNh[1], aNh[2], aNh[3], gs);
        float vNi = sel4(aNi[0], aNi[1], aNi[2], aNi[3], gs);
#pragma unroll
        for (int off = 4; off <= 32; off <<= 1) {
            vF  += __shfl_xor(vF,  off, 64);
            vNh += __shfl_xor(vNh, off, 64);
            vNi += __shfl_xor(vNi, off, 64);
        }

        // ---- gate + publish: lanes 0..3 -> units jb..jb+3 ----
        if (q < 4) {
            const float cF  = sel4(bFv[0],  bFv[1],  bFv[2],  bFv[3],  q);
            const float cIn = sel4(bInv[0], bInv[1], bInv[2], bInv[3], q);
            const float cHn = sel4(bHnv[0], bHnv[1], bHnv[2], bHnv[3], q);
            const int   j   = jb + q;
            const float hp  = hD[j];
            const float f   = 1.f / (1.f + expf(-(vF + cF)));
            const float n   = tanhf(vNi + cIn + f * (vNh + cHn));
            const float hy  = n + (1.f - f) * (hp - n);
            const u64   pk  = pack(hy, t + 1);
            agstore64(hpub + j, pk);                 // sc0 sc1: L2 + MALL
            if constexpr (L < 2) {
                agstore64(xring_out + (size_t)(t & (RING - 1)) * HDIM + j, pk);
            } else {
                xout[(size_t)t * HDIM + j] = hy;
            }
        }
        // no trailing barrier: parity LDS buffers + per-step barrier bound
        // intra-WG skew to 1 step.
    }
}

__global__ __launch_bounds__(512, 2)
void mgu_pipe(const float* __restrict__ S,
              const float* __restrict__ h0,
              const float* __restrict__ w_ih0, const float* __restrict__ b_ih0,
              const float* __restrict__ w_hh0, const float* __restrict__ b_hh0,
              const float* __restrict__ w_ih_r, const float* __restrict__ b_ih_r,
              const float* __restrict__ w_hh_r, const float* __restrict__ b_hh_r,
              float* __restrict__ xbuf2, u64* __restrict__ ring0,
              u64* __restrict__ ring1, u64* __restrict__ htag,
              int* __restrict__ prog)
{
    __shared__ __align__(16) float    s_h[2 * HDIM];      // 8 KB
    __shared__ __align__(16) float    s_x[2 * HDIM];      // 8 KB
    __shared__ __align__(16) unsigned s_wih[64 * 512];    // 128 KB bf16 pairs
    const int xcd  = blockIdx.x & 7;    // round-robin XCD mapping
    const int slot = blockIdx.x >> 3;   // 0..31 within XCD
    if (xcd == 0) {
        scan_layer<128, 0>(s_h, s_x, s_wih, S, nullptr, ring0, nullptr, h0,
                           w_ih0, b_ih0, w_hh0, b_hh0,
                           htag, prog + 1, nullptr, slot);
    } else if (xcd == 1) {
        scan_layer<1024, 1>(s_h, s_x, s_wih, nullptr, ring0, ring1, nullptr,
                            h0 + HDIM, w_ih_r, b_ih_r, w_hh_r, b_hh_r,
                            htag + 2 * HDIM, prog + 2, prog + 1, slot);
    } else if (xcd == 2) {
        scan_layer<1024, 2>(s_h, s_x, s_wih, nullptr, ring1, nullptr, xbuf2,
                            h0 + 2 * HDIM,
                            w_ih_r + 2048 * 1024, b_ih_r + 2048,
                            w_hh_r + 2048 * 1024, b_hh_r + 2048,
                            htag + 4 * HDIM, nullptr, prog + 2, slot);
    }
    // xcd 3..7: exit immediately (160 idle WGs free their CUs)
}

__global__ __launch_bounds__(256)
void mgu_out(const float* __restrict__ x,       // [T, H]
             const float* __restrict__ w_out,   // [1, H]
             const float* __restrict__ b_out,   // [1]
             float* __restrict__ out)           // [T]
{
    const int wave = threadIdx.x >> 6;
    const int lane = threadIdx.x & 63;
    const int t = blockIdx.x * 4 + wave;
    float acc = 0.f;
#pragma unroll
    for (int m = 0; m < 4; ++m) {
        const int i4 = lane + 64 * m;
        const float4 x4 = ((const float4*)(x + (size_t)t * HDIM))[i4];
        const float4 w4 = ((const float4*)w_out)[i4];
        acc += dot4(x4, w4);
    }
#pragma unroll
    for (int off = 32; off > 0; off >>= 1) acc += __shfl_xor(acc, off, 64);
    if (lane == 0) out[t] = acc + b_out[0];
}

extern "C" void kernel_launch(void* const* d_in, const int* in_sizes, int n_in,
                              void* d_out, int out_size, void* d_ws, size_t ws_size,
                              hipStream_t stream) {
    const float* S      = (const float*)d_in[0];   // [8192,128]
    const float* h0     = (const float*)d_in[1];   // [3,1024]
    const float* w_ih0  = (const float*)d_in[2];   // [2048,128]
    const float* w_hh0  = (const float*)d_in[3];   // [2048,1024]
    const float* b_ih0  = (const float*)d_in[4];   // [2048]
    const float* b_hh0  = (const float*)d_in[5];   // [2048]
    const float* w_ih_r = (const float*)d_in[6];   // [2,2048,1024]
    const float* w_hh_r = (const float*)d_in[7];   // [2,2048,1024]
    const float* b_ih_r = (const float*)d_in[8];   // [2,2048]
    const float* b_hh_r = (const float*)d_in[9];   // [2,2048]
    const float* w_out  = (const float*)d_in[10];  // [1,1024]
    const float* b_out  = (const float*)d_in[11];  // [1]
    float* out = (float*)d_out;                    // [8192]

    char* ws = (char*)d_ws;
    float* xbuf2 = (float*)(ws);                        // 32 MB  [T,H] f32
    u64*   ring0 = (u64*)(ws + (32u << 20));            // 1 MB   [RING,H] u64
    u64*   ring1 = (u64*)(ws + (33u << 20));            // 1 MB
    u64*   htag  = (u64*)(ws + (34u << 20));            // 3 x [2,H] u64
    int*   prog  = (int*)(ws + (34u << 20) + (64u << 10));

    // No init kernel: tags/progress use exact-match vs the 0xAA poison.
    mgu_pipe<<<256, 512, 0, stream>>>(S, h0, w_ih0, b_ih0, w_hh0, b_hh0,
                                      w_ih_r, b_ih_r, w_hh_r, b_hh_r,
                                      xbuf2, ring0, ring1, htag, prog);
    mgu_out<<<2048, 256, 0, stream>>>(xbuf2, w_out, b_out, out);
}

// Round 9
// 35719.672 us; speedup vs baseline: 1.2708x; 1.2708x over previous
//
#include <hip/hip_runtime.h>
#include <math.h>
#include <stdint.h>

// MGU RNN, T=8192, IN=128, H=1024, L=3 — R9: XCD-local h-chain, fixed.
// Layer l on XCD l (blockIdx%8 round-robin): 32 WGs x 512 thr, 1 WG/CU
// (144KB LDS forces it). Wave a of WG slot owns units jb=32*slot+4a..+3.
// R9 fixes vs R8 (45ms: stale-L2 h polls + 2.7e8 LDS conflicts):
//  - h publish: PLAIN (workgroup-scope) store -> producer's per-XCD L2,
//    the coherence point for the XCD; consumers poll sc0 (bypass L1, read
//    L2). PLUS a MALL mirror (sc0 sc1, separate address) polled every 8th
//    sweep: if %8 placement is wrong we degrade to ~R6 speed, not deadlock.
//  - W_ih bf16 LDS layout lane-contiguous ([u][gate][m][q] dword pairs ->
//    banks {2q,2q+1}, 2-way aliasing = free) -> conflicts ~0.
//  - x polled + x-dots computed BEFORE the h wait (two barriers/step):
//    W_ih work hides behind peers' h-store drain.
// Tag fabric (validated R3-R8): (tag<<32|float-bits) u64 words, exact-match
// tags (0xAA poison never matches -> no init); parity-2 h rows; 128-row
// MALL x rings with amortized backpressure via progress words.

#define T_STEPS 8192
#define HDIM 1024
#define RING 128

typedef unsigned long long u64;
typedef int v4i __attribute__((ext_vector_type(4)));

__device__ __forceinline__ void agstore64(u64* p, u64 v) {
    __hip_atomic_store(p, v, __ATOMIC_RELAXED, __HIP_MEMORY_SCOPE_AGENT);
}
__device__ __forceinline__ int agloadi(const int* p) {
    return __hip_atomic_load(p, __ATOMIC_RELAXED, __HIP_MEMORY_SCOPE_AGENT);
}
__device__ __forceinline__ void agstorei(int* p, int v) {
    __hip_atomic_store(p, v, __ATOMIC_RELAXED, __HIP_MEMORY_SCOPE_AGENT);
}
// plain store: write-through L1 -> lands in this XCD's L2 (local coherence pt)
__device__ __forceinline__ void l2store64(u64* p, u64 v) {
    __hip_atomic_store(p, v, __ATOMIC_RELAXED, __HIP_MEMORY_SCOPE_WORKGROUP);
}
// same-XCD poll: sc0 bypasses L1, reads the (coherent) local L2
__device__ __forceinline__ v4i poll_l2(const u64* p) {
    v4i r;
    asm volatile("global_load_dwordx4 %0, %1, off sc0\n\t"
                 "s_waitcnt vmcnt(0)"
                 : "=v"(r) : "v"(p) : "memory");
    return r;
}
// MALL poll: sc0 sc1 bypass L1+L2 — cross-XCD truth
__device__ __forceinline__ v4i poll_mall(const u64* p) {
    v4i r;
    asm volatile("global_load_dwordx4 %0, %1, off sc0 sc1\n\t"
                 "s_waitcnt vmcnt(0)"
                 : "=v"(r) : "v"(p) : "memory");
    return r;
}
__device__ __forceinline__ float dot4(float4 a, float4 b) {
    return a.x * b.x + a.y * b.y + a.z * b.z + a.w * b.w;
}
__device__ __forceinline__ u64 pack(float v, int tag) {
    return ((u64)(unsigned)tag << 32) | (u64)__float_as_uint(v);
}
__device__ __forceinline__ void opaque4(float4& v) {
    asm volatile("" : "+v"(v.x), "+v"(v.y), "+v"(v.z), "+v"(v.w));
}
__device__ __forceinline__ void opaque2(float2& v) {
    asm volatile("" : "+v"(v.x), "+v"(v.y));
}
__device__ __forceinline__ float sel4(float a0, float a1, float a2, float a3, int g) {
    const float t01 = (g & 1) ? a1 : a0;
    const float t23 = (g & 1) ? a3 : a2;
    return (g & 2) ? t23 : t01;
}
// fp32 -> bf16 bits, round-to-nearest-even
__device__ __forceinline__ unsigned short f2bf(float f) {
    unsigned u = __float_as_uint(f);
    return (unsigned short)((u + 0x7fffu + ((u >> 16) & 1u)) >> 16);
}
// acc += bf16lo(w)*x0 + bf16hi(w)*x1
__device__ __forceinline__ void fma2(float& acc, unsigned w, float x0, float x1) {
    acc += __uint_as_float(w << 16) * x0;
    acc += __uint_as_float(w & 0xffff0000u) * x1;
}

// K: input width. L: layer index 0..2.
template <int K, int L>
__device__ void scan_layer(float* __restrict__ s_h,       // [2][HDIM]
                           float* __restrict__ s_x,       // [2][HDIM]
                           unsigned* __restrict__ s_wih,  // [32768] bf16 pairs
                           const float* __restrict__ S,         // L==0
                           const u64*  __restrict__ xring_in,   // L>0
                           u64*        __restrict__ xring_out,  // L<2
                           float*      __restrict__ xout,       // L==2
                           const float* __restrict__ h0,
                           const float* __restrict__ w_ih,
                           const float* __restrict__ b_ih,
                           const float* __restrict__ w_hh,
                           const float* __restrict__ b_hh,
                           u64* __restrict__ htag,              // [2,H] local
                           u64* __restrict__ htag_m,            // [2,H] mirror
                           int* __restrict__ progNext,          // L<2
                           int* __restrict__ progSelf,          // L>0
                           int slot)                            // 0..31
{
    const int tid = threadIdx.x;       // 0..511
    const int a   = tid >> 6;          // wave 0..7
    const int q   = tid & 63;          // lane
    const int jb  = slot * 32 + 4 * a; // wave owns units jb..jb+3
    const int base = slot * 32;

    // ---- W_ih -> LDS bf16 pairs, lane-contiguous layout (K==1024) ----
    // dword index = ((((u*2+gate)*4+m)*64)+q)*2+d ; elem e = 4q+256m+2d.
    if constexpr (K == 1024) {
#pragma unroll 4
        for (int it = 0; it < 64; ++it) {
            const int flat = tid + 512 * it;
            const int d    = flat & 1;
            const int qq   = (flat >> 1) & 63;
            const int m    = (flat >> 7) & 3;
            const int gate = (flat >> 9) & 1;
            const int u    = flat >> 10;            // 0..31
            const int e    = 4 * qq + 256 * m + 2 * d;
            const int grow = gate ? (HDIM + base + u) : (base + u);
            const float2 v = *(const float2*)(w_ih + (size_t)grow * K + e);
            s_wih[flat] = (unsigned)f2bf(v.x) | ((unsigned)f2bf(v.y) << 16);
        }
    }

    // ---- W_hh rows jb+g (f), H+jb+g (n) -> 128 pinned floats (AGPRs) ----
    float4 wf[4][4], wn[4][4];
#pragma unroll
    for (int g = 0; g < 4; ++g) {
        const float* rf = w_hh + (size_t)(jb + g) * HDIM;
        const float* rn = w_hh + (size_t)(HDIM + jb + g) * HDIM;
#pragma unroll
        for (int m = 0; m < 4; ++m) {
            wf[g][m] = *(const float4*)(rf + 4 * q + 256 * m);
            wn[g][m] = *(const float4*)(rn + 4 * q + 256 * m);
            opaque4(wf[g][m]); opaque4(wn[g][m]);
        }
    }
    float2 wif2[4], win2[4];   // K==128 input weights (fp32 regs)
    if constexpr (K == 128) {
#pragma unroll
        for (int g = 0; g < 4; ++g) {
            wif2[g] = *(const float2*)(w_ih + (size_t)(jb + g) * K + 2 * q);
            win2[g] = *(const float2*)(w_ih + (size_t)(HDIM + jb + g) * K + 2 * q);
            opaque2(wif2[g]); opaque2(win2[g]);
        }
    }
    float bFv[4], bInv[4], bHnv[4];
#pragma unroll
    for (int g = 0; g < 4; ++g) {
        bFv[g]  = b_ih[jb + g] + b_hh[jb + g];
        bInv[g] = b_ih[HDIM + jb + g];
        bHnv[g] = b_hh[HDIM + jb + g];
    }
    __syncthreads();   // s_wih staged

    int lastProg = 0;
    for (int t = 0; t < T_STEPS; ++t) {
        const int par = t & 1;
        const u64* hrow  = htag   + (size_t)((t + 1) & 1) * HDIM;  // parity t-1
        const u64* hrowm = htag_m + (size_t)((t + 1) & 1) * HDIM;
        float* hD = s_h + par * HDIM;
        float* xD = s_x + par * HDIM;

        // ---- ring backpressure (MALL, amortized, off critical path) ----
        if constexpr (L < 2) {
            if (t - lastProg > RING - 16) {
                do { lastProg = agloadi(progNext); } while (t - lastProg > RING - 16);
            }
        }

        // ---- phase A: x (ring producer runs ahead -> first-sweep hit) ----
        if constexpr (L > 0) {
            const u64* xp = xring_in + (size_t)(t & (RING - 1)) * HDIM + 2 * tid;
            const unsigned xe = (unsigned)(t + 1);
            for (;;) {
                const v4i v = poll_mall(xp);
                if ((unsigned)v.y == xe && (unsigned)v.w == xe) {
                    ((float2*)xD)[tid] =
                        make_float2(__int_as_float(v.x), __int_as_float(v.z));
                    break;
                }
            }
        } else {
            if (tid < K / 4)
                ((float4*)xD)[tid] = ((const float4*)(S + (size_t)t * K))[tid];
        }
        __syncthreads();   // barrier 1: xD staged

        if constexpr (L > 0) {
            if (slot == 0 && tid == 0) agstorei(progSelf, t + 1);
        }

        // ---- x-dots (hide behind peers' h-store drain) ----
        float aF[4]  = {0.f, 0.f, 0.f, 0.f};
        float aNh[4] = {0.f, 0.f, 0.f, 0.f};
        float aNi[4] = {0.f, 0.f, 0.f, 0.f};
        if constexpr (K == 1024) {
#pragma unroll
            for (int m = 0; m < 4; ++m) {
                const float4 x4 = ((const float4*)xD)[q + 64 * m];
#pragma unroll
                for (int g = 0; g < 4; ++g) {
                    const int u = 4 * a + g;
                    const uint2 wF = *(const uint2*)
                        &s_wih[((((u * 2 + 0) * 4 + m) * 64) + q) * 2];
                    const uint2 wN = *(const uint2*)
                        &s_wih[((((u * 2 + 1) * 4 + m) * 64) + q) * 2];
                    fma2(aF[g],  wF.x, x4.x, x4.y);
                    fma2(aF[g],  wF.y, x4.z, x4.w);
                    fma2(aNi[g], wN.x, x4.x, x4.y);
                    fma2(aNi[g], wN.y, x4.z, x4.w);
                }
            }
        } else {
            const float2 x2 = ((const float2*)xD)[q];
#pragma unroll
            for (int g = 0; g < 4; ++g) {
                aF[g]  += wif2[g].x * x2.x + wif2[g].y * x2.y;
                aNi[g] += win2[g].x * x2.x + win2[g].y * x2.y;
            }
        }

        // ---- phase B: h_{t-1} — local-L2 poll + every-8th MALL mirror ----
        if (t == 0) {
            ((float2*)hD)[tid] = ((const float2*)h0)[tid];
        } else {
            const u64* hp = hrow  + 2 * tid;
            const u64* hm = hrowm + 2 * tid;
            const unsigned he = (unsigned)t;
            int sweep = 0;
            for (;;) {
                v4i v = poll_l2(hp);
                if ((unsigned)v.y == he && (unsigned)v.w == he) {
                    ((float2*)hD)[tid] =
                        make_float2(__int_as_float(v.x), __int_as_float(v.z));
                    break;
                }
                if (((++sweep) & 7) == 0) {
                    v = poll_mall(hm);
                    if ((unsigned)v.y == he && (unsigned)v.w == he) {
                        ((float2*)hD)[tid] =
                            make_float2(__int_as_float(v.x), __int_as_float(v.z));
                        break;
                    }
                }
            }
        }
        __syncthreads();   // barrier 2: hD staged

        // ---- h-dots (W_hh from pinned regs; conflict-free b128 LDS) ----
#pragma unroll
        for (int m = 0; m < 4; ++m) {
            const float4 h4 = ((const float4*)hD)[q + 64 * m];
#pragma unroll
            for (int g = 0; g < 4; ++g) {
                aF[g]  += dot4(wf[g][m], h4);
                aNh[g] += dot4(wn[g][m], h4);
            }
        }

        // ---- two-phase reduction: quad butterfly, select, stride ----
#pragma unroll
        for (int g = 0; g < 4; ++g) {
            aF[g]  += __shfl_xor(aF[g], 1, 64);  aF[g]  += __shfl_xor(aF[g], 2, 64);
            aNh[g] += __shfl_xor(aNh[g], 1, 64); aNh[g] += __shfl_xor(aNh[g], 2, 64);
            aNi[g] += __shfl_xor(aNi[g], 1, 64); aNi[g] += __shfl_xor(aNi[g], 2, 64);
        }
        const int gs = q & 3;
        float vF  = sel4(aF[0],  aF[1],  aF[2],  aF[3],  gs);
        float vNh = sel4(aNh[0], aNh[1], aNh[2], aNh[3], gs);
        float vNi = sel4(aNi[0], aNi[1], aNi[2], aNi[3], gs);
#pragma unroll
        for (int off = 4; off <= 32; off <<= 1) {
            vF  += __shfl_xor(vF,  off, 64);
            vNh += __shfl_xor(vNh, off, 64);
            vNi += __shfl_xor(vNi, off, 64);
        }

        // ---- gate + publish: lanes 0..3 -> units jb..jb+3 ----
        if (q < 4) {
            const float cF  = sel4(bFv[0],  bFv[1],  bFv[2],  bFv[3],  q);
            const float cIn = sel4(bInv[0], bInv[1], bInv[2], bInv[3], q);
            const float cHn = sel4(bHnv[0], bHnv[1], bHnv[2], bHnv[3], q);
            const int   j   = jb + q;
            const float hp  = hD[j];
            const float f   = 1.f / (1.f + expf(-(vF + cF)));
            const float n   = tanhf(vNi + cIn + f * (vNh + cHn));
            const float hy  = n + (1.f - f) * (hp - n);
            const u64   pk  = pack(hy, t + 1);
            l2store64(htag   + (size_t)par * HDIM + j, pk);  // local L2 (fast path)
            agstore64(htag_m + (size_t)par * HDIM + j, pk);  // MALL mirror
            if constexpr (L < 2) {
                agstore64(xring_out + (size_t)(t & (RING - 1)) * HDIM + j, pk);
            } else {
                xout[(size_t)t * HDIM + j] = hy;
            }
        }
        // no trailing barrier: parity LDS buffers + the two per-step
        // barriers bound intra-WG skew to 1 step.
    }
}

__global__ __launch_bounds__(512, 2)
void mgu_pipe(const float* __restrict__ S,
              const float* __restrict__ h0,
              const float* __restrict__ w_ih0, const float* __restrict__ b_ih0,
              const float* __restrict__ w_hh0, const float* __restrict__ b_hh0,
              const float* __restrict__ w_ih_r, const float* __restrict__ b_ih_r,
              const float* __restrict__ w_hh_r, const float* __restrict__ b_hh_r,
              float* __restrict__ xbuf2, u64* __restrict__ ring0,
              u64* __restrict__ ring1, u64* __restrict__ htag,
              u64* __restrict__ htag_m, int* __restrict__ prog)
{
    __shared__ __align__(16) float    s_h[2 * HDIM];   // 8 KB
    __shared__ __align__(16) float    s_x[2 * HDIM];   // 8 KB
    __shared__ __align__(16) unsigned s_wih[32768];    // 128 KB bf16 pairs
    const int xcd  = blockIdx.x & 7;    // round-robin XCD mapping
    const int slot = blockIdx.x >> 3;   // 0..31 within XCD
    if (xcd == 0) {
        scan_layer<128, 0>(s_h, s_x, s_wih, S, nullptr, ring0, nullptr, h0,
                           w_ih0, b_ih0, w_hh0, b_hh0,
                           htag, htag_m, prog + 1, nullptr, slot);
    } else if (xcd == 1) {
        scan_layer<1024, 1>(s_h, s_x, s_wih, nullptr, ring0, ring1, nullptr,
                            h0 + HDIM, w_ih_r, b_ih_r, w_hh_r, b_hh_r,
                            htag + 2 * HDIM, htag_m + 2 * HDIM,
                            prog + 2, prog + 1, slot);
    } else if (xcd == 2) {
        scan_layer<1024, 2>(s_h, s_x, s_wih, nullptr, ring1, nullptr, xbuf2,
                            h0 + 2 * HDIM,
                            w_ih_r + 2048 * 1024, b_ih_r + 2048,
                            w_hh_r + 2048 * 1024, b_hh_r + 2048,
                            htag + 4 * HDIM, htag_m + 4 * HDIM,
                            nullptr, prog + 2, slot);
    }
    // xcd 3..7: exit immediately
}

__global__ __launch_bounds__(256)
void mgu_out(const float* __restrict__ x,       // [T, H]
             const float* __restrict__ w_out,   // [1, H]
             const float* __restrict__ b_out,   // [1]
             float* __restrict__ out)           // [T]
{
    const int wave = threadIdx.x >> 6;
    const int lane = threadIdx.x & 63;
    const int t = blockIdx.x * 4 + wave;
    float acc = 0.f;
#pragma unroll
    for (int m = 0; m < 4; ++m) {
        const int i4 = lane + 64 * m;
        const float4 x4 = ((const float4*)(x + (size_t)t * HDIM))[i4];
        const float4 w4 = ((const float4*)w_out)[i4];
        acc += dot4(x4, w4);
    }
#pragma unroll
    for (int off = 32; off > 0; off >>= 1) acc += __shfl_xor(acc, off, 64);
    if (lane == 0) out[t] = acc + b_out[0];
}

extern "C" void kernel_launch(void* const* d_in, const int* in_sizes, int n_in,
                              void* d_out, int out_size, void* d_ws, size_t ws_size,
                              hipStream_t stream) {
    const float* S      = (const float*)d_in[0];   // [8192,128]
    const float* h0     = (const float*)d_in[1];   // [3,1024]
    const float* w_ih0  = (const float*)d_in[2];   // [2048,128]
    const float* w_hh0  = (const float*)d_in[3];   // [2048,1024]
    const float* b_ih0  = (const float*)d_in[4];   // [2048]
    const float* b_hh0  = (const float*)d_in[5];   // [2048]
    const float* w_ih_r = (const float*)d_in[6];   // [2,2048,1024]
    const float* w_hh_r = (const float*)d_in[7];   // [2,2048,1024]
    const float* b_ih_r = (const float*)d_in[8];   // [2,2048]
    const float* b_hh_r = (const float*)d_in[9];   // [2,2048]
    const float* w_out  = (const float*)d_in[10];  // [1,1024]
    const float* b_out  = (const float*)d_in[11];  // [1]
    float* out = (float*)d_out;                    // [8192]

    char* ws = (char*)d_ws;
    float* xbuf2  = (float*)(ws);                         // 32 MB  [T,H] f32
    u64*   ring0  = (u64*)(ws + (32u << 20));             // 1 MB
    u64*   ring1  = (u64*)(ws + (33u << 20));             // 1 MB
    u64*   htag   = (u64*)(ws + (34u << 20));             // 48 KB local
    u64*   htag_m = (u64*)(ws + (34u << 20) + (64u << 10)); // 48 KB mirror
    int*   prog   = (int*)(ws + (34u << 20) + (128u << 10));

    // No init kernel: tags/progress use exact-match vs the 0xAA poison.
    mgu_pipe<<<256, 512, 0, stream>>>(S, h0, w_ih0, b_ih0, w_hh0, b_hh0,
                                      w_ih_r, b_ih_r, w_hh_r, b_hh_r,
                                      xbuf2, ring0, ring1, htag, htag_m, prog);
    mgu_out<<<2048, 256, 0, stream>>>(xbuf2, w_out, b_out, out);
}